// Round 1
// baseline (85.549 us; speedup 1.0000x reference)
//
#include <hip/hip_runtime.h>

typedef __bf16 bf16x8 __attribute__((ext_vector_type(8)));
typedef float f32x4 __attribute__((ext_vector_type(4)));

#define D_DIM 256
#define INV_T 2.0f

__device__ __forceinline__ unsigned short f2bf(float f) {
  union { float f; unsigned u; } x; x.f = f;
  unsigned r = x.u + 0x7FFFu + ((x.u >> 16) & 1u);  // round-to-nearest-even
  return (unsigned short)(r >> 16);
}

// ---------------- Kernel 1: L2-normalize [emb_i; emb_j] -> bf16 R[N][256] ----
__global__ __launch_bounds__(256) void k_normalize(const float* __restrict__ ei,
                                                   const float* __restrict__ ej,
                                                   unsigned short* __restrict__ R,
                                                   int B) {
  const int w = threadIdx.x >> 6, lane = threadIdx.x & 63;
  const int row = blockIdx.x * 4 + w;
  const float* src = (row < B) ? (ei + (size_t)row * D_DIM)
                               : (ej + (size_t)(row - B) * D_DIM);
  float4 v = reinterpret_cast<const float4*>(src)[lane];  // 64 lanes * 4 = 256
  float ss = v.x * v.x + v.y * v.y + v.z * v.z + v.w * v.w;
#pragma unroll
  for (int d = 32; d; d >>= 1) ss += __shfl_xor(ss, d, 64);
  float s = 1.0f / fmaxf(sqrtf(ss), 1e-12f);
  ushort4 o;
  o.x = f2bf(v.x * s); o.y = f2bf(v.y * s);
  o.z = f2bf(v.z * s); o.w = f2bf(v.w * s);
  reinterpret_cast<ushort4*>(R + (size_t)row * D_DIM)[lane] = o;
}

// ---------------- Kernel 2: fused sim GEMM + exp-row-partials ---------------
// sim = (R R^T) * INV_T ; per 128x128 tile: zero diag, record target entry,
// sum exp along columns, write per-(colblock,wavecol) row partials.
__global__ __launch_bounds__(256, 2) void k_simgemm(const unsigned short* __restrict__ R,
                                                    float* __restrict__ rowPartial,
                                                    float* __restrict__ simTgt,
                                                    int N) {
  __shared__ char lds[2][32 * 1024];  // per buf: A tile 16KB + B tile 16KB
  const int tid = threadIdx.x;
  const int w = tid >> 6, lane = tid & 63;
  const int wr = w >> 1, wc = w & 1;
  const int brow = blockIdx.y * 128, bcol = blockIdx.x * 128;
  const int half = N >> 1;

  f32x4 zero4 = {0.f, 0.f, 0.f, 0.f};
  f32x4 acc[4][4];
#pragma unroll
  for (int m = 0; m < 4; ++m)
#pragma unroll
    for (int n = 0; n < 4; ++n) acc[m][n] = zero4;

  // stage one BK=64 K-slice of the A (rows) and B (cols) panels into LDS.
  // Linear LDS dest (global_load_lds requirement) + inverse-XOR-swizzled
  // global source; reads apply the same swizzle (rule #21 both-sides).
  auto stage = [&](int buf, int kt) {
    char* ldsA = lds[buf];
    char* ldsB = lds[buf] + 16 * 1024;
#pragma unroll
    for (int i = 0; i < 4; ++i) {
      const int grp = i * 4 + w;          // 16 chunk-groups of 64
      const int c = grp * 64 + lane;      // chunk id 0..1023
      const int r = c >> 3, j = c & 7;
      const int k8 = j ^ (r & 7);         // inverse swizzle on source
      const unsigned short* gA = R + (size_t)(brow + r) * D_DIM + kt * 64 + k8 * 8;
      const unsigned short* gB = R + (size_t)(bcol + r) * D_DIM + kt * 64 + k8 * 8;
      __builtin_amdgcn_global_load_lds(
          (const __attribute__((address_space(1))) void*)gA,
          (__attribute__((address_space(3))) void*)(ldsA + (size_t)grp * 1024), 16, 0, 0);
      __builtin_amdgcn_global_load_lds(
          (const __attribute__((address_space(1))) void*)gB,
          (__attribute__((address_space(3))) void*)(ldsB + (size_t)grp * 1024), 16, 0, 0);
    }
  };

  auto compute = [&](int buf) {
    const char* ldsA = lds[buf];
    const char* ldsB = lds[buf] + 16 * 1024;
#pragma unroll
    for (int kk = 0; kk < 2; ++kk) {
      const int k8 = kk * 4 + (lane >> 4);
      bf16x8 a[4], b[4];
#pragma unroll
      for (int m = 0; m < 4; ++m) {
        const int row = wr * 64 + m * 16 + (lane & 15);
        a[m] = *reinterpret_cast<const bf16x8*>(ldsA + (row * 8 + (k8 ^ (row & 7))) * 16);
      }
#pragma unroll
      for (int n = 0; n < 4; ++n) {
        const int col = wc * 64 + n * 16 + (lane & 15);
        b[n] = *reinterpret_cast<const bf16x8*>(ldsB + (col * 8 + (k8 ^ (col & 7))) * 16);
      }
#pragma unroll
      for (int m = 0; m < 4; ++m)
#pragma unroll
        for (int n = 0; n < 4; ++n)
          acc[m][n] = __builtin_amdgcn_mfma_f32_16x16x32_bf16(a[m], b[n], acc[m][n], 0, 0, 0);
    }
  };

  stage(0, 0);
  __syncthreads();
#pragma unroll
  for (int kt = 0; kt < 4; ++kt) {  // K = 256 = 4 * 64
    const int cur = kt & 1;
    if (kt < 3) stage(cur ^ 1, kt + 1);
    compute(cur);
    __syncthreads();
  }

  // epilogue: scale, mask diag, capture target, exp, per-row sum over tile cols
#pragma unroll
  for (int m = 0; m < 4; ++m) {
#pragma unroll
    for (int j = 0; j < 4; ++j) {
      const int gr = brow + wr * 64 + m * 16 + (lane >> 4) * 4 + j;
      const int tgt = (gr < half) ? gr + half : gr - half;
      float rs = 0.f;
#pragma unroll
      for (int n = 0; n < 4; ++n) {
        const int gc = bcol + wc * 64 + n * 16 + (lane & 15);
        const float sv = acc[m][n][j] * INV_T;
        if (gc == tgt) simTgt[gr] = sv;           // exactly one writer per row
        rs += (gr == gc) ? 0.f : __expf(sv);      // diagonal masked to -inf
      }
#pragma unroll
      for (int d = 1; d < 16; d <<= 1) rs += __shfl_xor(rs, d, 64);
      if ((lane & 15) == 0)
        rowPartial[(size_t)(blockIdx.x * 2 + wc) * N + gr] = rs;
    }
  }
}

// ---------------- Kernel 3: per-row logsumexp-target, block partial sums ----
__global__ __launch_bounds__(256) void k_rowreduce(const float* __restrict__ rowPartial,
                                                   const float* __restrict__ simTgt,
                                                   float* __restrict__ blockOut,
                                                   int N) {
  const int row = blockIdx.x * 256 + threadIdx.x;
  float denom = 0.f;
#pragma unroll 8
  for (int c = 0; c < 128; ++c) denom += rowPartial[(size_t)c * N + row];
  float lossr = __logf(denom) - simTgt[row];
#pragma unroll
  for (int d = 32; d; d >>= 1) lossr += __shfl_xor(lossr, d, 64);
  __shared__ float red[4];
  if ((threadIdx.x & 63) == 0) red[threadIdx.x >> 6] = lossr;
  __syncthreads();
  if (threadIdx.x == 0) blockOut[blockIdx.x] = red[0] + red[1] + red[2] + red[3];
}

// ---------------- Kernel 4: final mean ---------------------------------------
__global__ void k_final(const float* __restrict__ blockOut, float* __restrict__ out,
                        int nb, float invN) {
  float v = (threadIdx.x < nb) ? blockOut[threadIdx.x] : 0.f;
#pragma unroll
  for (int d = 32; d; d >>= 1) v += __shfl_xor(v, d, 64);
  if (threadIdx.x == 0) out[0] = v * invN;
}

extern "C" void kernel_launch(void* const* d_in, const int* in_sizes, int n_in,
                              void* d_out, int out_size, void* d_ws, size_t ws_size,
                              hipStream_t stream) {
  const float* ei = (const float*)d_in[0];
  const float* ej = (const float*)d_in[1];
  const int B = in_sizes[0] / D_DIM;  // 4096
  const int N = 2 * B;                // 8192

  char* ws = (char*)d_ws;
  unsigned short* R = (unsigned short*)ws;                                   // N*256*2 = 4MB
  float* rowPartial = (float*)(ws + (size_t)N * D_DIM * 2);                  // 128*N*4 = 4MB
  float* simTgt     = (float*)(ws + (size_t)N * D_DIM * 2 + (size_t)128 * N * 4);  // N*4
  float* blockOut   = (float*)((char*)simTgt + (size_t)N * 4);               // (N/256)*4

  k_normalize<<<N / 4, 256, 0, stream>>>(ei, ej, R, B);
  dim3 g2(N / 128, N / 128);
  k_simgemm<<<g2, 256, 0, stream>>>(R, rowPartial, simTgt, N);
  k_rowreduce<<<N / 256, 256, 0, stream>>>(rowPartial, simTgt, blockOut, N);
  k_final<<<1, 64, 0, stream>>>(blockOut, (float*)d_out, N / 256, 1.0f / (float)N);
}

// Round 2
// 66.053 us; speedup vs baseline: 1.2952x; 1.2952x over previous
//
#include <hip/hip_runtime.h>

typedef __bf16 bf16x8 __attribute__((ext_vector_type(8)));
typedef float f32x4 __attribute__((ext_vector_type(4)));

#define D_DIM 256
#define INV_T 2.0f

__device__ __forceinline__ unsigned short f2bf(float f) {
  union { float f; unsigned u; } x; x.f = f;
  unsigned r = x.u + 0x7FFFu + ((x.u >> 16) & 1u);  // round-to-nearest-even
  return (unsigned short)(r >> 16);
}

// ---------------- Kernel 1: L2-normalize [emb_i; emb_j] -> bf16 R[N][256] ----
__global__ __launch_bounds__(256) void k_normalize(const float* __restrict__ ei,
                                                   const float* __restrict__ ej,
                                                   unsigned short* __restrict__ R,
                                                   int B) {
  const int w = threadIdx.x >> 6, lane = threadIdx.x & 63;
  const int row = blockIdx.x * 4 + w;
  const float* src = (row < B) ? (ei + (size_t)row * D_DIM)
                               : (ej + (size_t)(row - B) * D_DIM);
  float4 v = reinterpret_cast<const float4*>(src)[lane];  // 64 lanes * 4 = 256
  float ss = v.x * v.x + v.y * v.y + v.z * v.z + v.w * v.w;
#pragma unroll
  for (int d = 32; d; d >>= 1) ss += __shfl_xor(ss, d, 64);
  float s = 1.0f / fmaxf(sqrtf(ss), 1e-12f);
  ushort4 o;
  o.x = f2bf(v.x * s); o.y = f2bf(v.y * s);
  o.z = f2bf(v.z * s); o.w = f2bf(v.w * s);
  reinterpret_cast<ushort4*>(R + (size_t)row * D_DIM)[lane] = o;
}

// ---------------- Kernel 2: symmetric fused sim GEMM + exp partials ---------
// Only upper-triangular 128x128 tiles (bi <= bj). Each off-diagonal tile
// contributes exp-sums to BOTH its row block (reduce along cols) and its
// column block (reduce along rows, by symmetry of sim). Slots:
//   rowPartial[o*2 + u][row], o = other block, u = wc (row-dir) / wr (col-dir)
// Diagonal tiles: row-dir only. Every (slot,row) written exactly once.
__global__ __launch_bounds__(256, 2) void k_simgemm(const unsigned short* __restrict__ R,
                                                    float* __restrict__ rowPartial,
                                                    float* __restrict__ simTgt,
                                                    int N) {
  __shared__ char lds[2][32 * 1024];  // per buf: A tile 16KB + B tile 16KB
  const int tid = threadIdx.x;
  const int w = tid >> 6, lane = tid & 63;
  const int wr = w >> 1, wc = w & 1;
  const int half = N >> 1;

  // decode linear block id -> upper-triangular (bi, bj), bi <= bj
  const int T = N / 128;  // 64
  const int t = blockIdx.x;
  int bi = (int)(((float)(2 * T + 1) -
                  sqrtf((float)((2 * T + 1) * (2 * T + 1) - 8 * t))) * 0.5f);
  // exact fixup (start(i) = i*(2T-i+1)/2)
  while (bi > 0 && t < bi * (2 * T - bi + 1) / 2) --bi;
  while (t >= (bi + 1) * (2 * T - bi) / 2) ++bi;
  const int bj = bi + (t - bi * (2 * T - bi + 1) / 2);
  const int brow = bi * 128, bcol = bj * 128;
  const bool offdiag = (bi != bj);

  f32x4 zero4 = {0.f, 0.f, 0.f, 0.f};
  f32x4 acc[4][4];
#pragma unroll
  for (int m = 0; m < 4; ++m)
#pragma unroll
    for (int n = 0; n < 4; ++n) acc[m][n] = zero4;

  // stage one BK=64 K-slice of the A (rows) and B (cols) panels into LDS.
  // Linear LDS dest (global_load_lds requirement) + inverse-XOR-swizzled
  // global source; reads apply the same swizzle (rule #21 both-sides).
  auto stage = [&](int buf, int kt) {
    char* ldsA = lds[buf];
    char* ldsB = lds[buf] + 16 * 1024;
#pragma unroll
    for (int i = 0; i < 4; ++i) {
      const int grp = i * 4 + w;          // 16 chunk-groups of 64
      const int c = grp * 64 + lane;      // chunk id 0..1023
      const int r = c >> 3, j = c & 7;
      const int k8 = j ^ (r & 7);         // inverse swizzle on source
      const unsigned short* gA = R + (size_t)(brow + r) * D_DIM + kt * 64 + k8 * 8;
      const unsigned short* gB = R + (size_t)(bcol + r) * D_DIM + kt * 64 + k8 * 8;
      __builtin_amdgcn_global_load_lds(
          (const __attribute__((address_space(1))) void*)gA,
          (__attribute__((address_space(3))) void*)(ldsA + (size_t)grp * 1024), 16, 0, 0);
      __builtin_amdgcn_global_load_lds(
          (const __attribute__((address_space(1))) void*)gB,
          (__attribute__((address_space(3))) void*)(ldsB + (size_t)grp * 1024), 16, 0, 0);
    }
  };

  auto compute = [&](int buf) {
    const char* ldsA = lds[buf];
    const char* ldsB = lds[buf] + 16 * 1024;
#pragma unroll
    for (int kk = 0; kk < 2; ++kk) {
      const int k8 = kk * 4 + (lane >> 4);
      bf16x8 a[4], b[4];
#pragma unroll
      for (int m = 0; m < 4; ++m) {
        const int row = wr * 64 + m * 16 + (lane & 15);
        a[m] = *reinterpret_cast<const bf16x8*>(ldsA + (row * 8 + (k8 ^ (row & 7))) * 16);
      }
#pragma unroll
      for (int n = 0; n < 4; ++n) {
        const int col = wc * 64 + n * 16 + (lane & 15);
        b[n] = *reinterpret_cast<const bf16x8*>(ldsB + (col * 8 + (k8 ^ (col & 7))) * 16);
      }
#pragma unroll
      for (int m = 0; m < 4; ++m)
#pragma unroll
        for (int n = 0; n < 4; ++n)
          acc[m][n] = __builtin_amdgcn_mfma_f32_16x16x32_bf16(a[m], b[n], acc[m][n], 0, 0, 0);
    }
  };

  stage(0, 0);
  __syncthreads();
#pragma unroll
  for (int kt = 0; kt < 4; ++kt) {  // K = 256 = 4 * 64
    const int cur = kt & 1;
    if (kt < 3) stage(cur ^ 1, kt + 1);
    compute(cur);
    __syncthreads();
  }

  // epilogue: scale, mask diag, capture targets (both directions), exp,
  // row-direction sums (over tile cols) + column-direction sums (over rows)
  float cs[4] = {0.f, 0.f, 0.f, 0.f};
#pragma unroll
  for (int m = 0; m < 4; ++m) {
#pragma unroll
    for (int j = 0; j < 4; ++j) {
      const int gr = brow + wr * 64 + m * 16 + (lane >> 4) * 4 + j;
      const int tgt = (gr < half) ? gr + half : gr - half;
      float rs = 0.f;
#pragma unroll
      for (int n = 0; n < 4; ++n) {
        const int gc = bcol + wc * 64 + n * 16 + (lane & 15);
        const float sv = acc[m][n][j] * INV_T;
        const float ev = (gr == gc) ? 0.f : __expf(sv);
        if (gc == tgt) {                 // involution: also gr == tgt(gc)
          simTgt[gr] = sv;
          if (offdiag) simTgt[gc] = sv;  // sim symmetric: sim[gc][gr] == sv
        }
        rs += ev;
        cs[n] += ev;
      }
#pragma unroll
      for (int d = 1; d < 16; d <<= 1) rs += __shfl_xor(rs, d, 64);
      if ((lane & 15) == 0)
        rowPartial[(size_t)(bj * 2 + wc) * N + gr] = rs;
    }
  }
  if (offdiag) {  // column block receives row-sums of the transposed tile
#pragma unroll
    for (int n = 0; n < 4; ++n) {
      float c = cs[n];
      c += __shfl_xor(c, 16, 64);
      c += __shfl_xor(c, 32, 64);
      if ((lane >> 4) == 0)
        rowPartial[(size_t)(bi * 2 + wr) * N + (bcol + wc * 64 + n * 16 + lane)] = c;
    }
  }
}

// ---------------- Kernel 3: per-row logsumexp-target, block partial sums ----
__global__ __launch_bounds__(256) void k_rowreduce(const float* __restrict__ rowPartial,
                                                   const float* __restrict__ simTgt,
                                                   float* __restrict__ blockOut,
                                                   int N) {
  const int row = blockIdx.x * 256 + threadIdx.x;
  float denom = 0.f;
#pragma unroll 8
  for (int c = 0; c < 128; ++c) denom += rowPartial[(size_t)c * N + row];
  float lossr = __logf(denom) - simTgt[row];
#pragma unroll
  for (int d = 32; d; d >>= 1) lossr += __shfl_xor(lossr, d, 64);
  __shared__ float red[4];
  if ((threadIdx.x & 63) == 0) red[threadIdx.x >> 6] = lossr;
  __syncthreads();
  if (threadIdx.x == 0) blockOut[blockIdx.x] = red[0] + red[1] + red[2] + red[3];
}

// ---------------- Kernel 4: final mean ---------------------------------------
__global__ void k_final(const float* __restrict__ blockOut, float* __restrict__ out,
                        int nb, float invN) {
  float v = (threadIdx.x < nb) ? blockOut[threadIdx.x] : 0.f;
#pragma unroll
  for (int d = 32; d; d >>= 1) v += __shfl_xor(v, d, 64);
  if (threadIdx.x == 0) out[0] = v * invN;
}

extern "C" void kernel_launch(void* const* d_in, const int* in_sizes, int n_in,
                              void* d_out, int out_size, void* d_ws, size_t ws_size,
                              hipStream_t stream) {
  const float* ei = (const float*)d_in[0];
  const float* ej = (const float*)d_in[1];
  const int B = in_sizes[0] / D_DIM;  // 4096
  const int N = 2 * B;                // 8192

  char* ws = (char*)d_ws;
  unsigned short* R = (unsigned short*)ws;                                   // N*256*2 = 4MB
  float* rowPartial = (float*)(ws + (size_t)N * D_DIM * 2);                  // 128*N*4 = 4MB
  float* simTgt     = (float*)(ws + (size_t)N * D_DIM * 2 + (size_t)128 * N * 4);  // N*4
  float* blockOut   = (float*)((char*)simTgt + (size_t)N * 4);               // (N/256)*4

  k_normalize<<<N / 4, 256, 0, stream>>>(ei, ej, R, B);
  const int T = N / 128;
  k_simgemm<<<T * (T + 1) / 2, 256, 0, stream>>>(R, rowPartial, simTgt, N);
  k_rowreduce<<<N / 256, 256, 0, stream>>>(rowPartial, simTgt, blockOut, N);
  k_final<<<1, 64, 0, stream>>>(blockOut, (float*)d_out, N / 256, 1.0f / (float)N);
}

// Round 3
// 53.382 us; speedup vs baseline: 1.6026x; 1.2374x over previous
//
#include <hip/hip_runtime.h>

typedef __bf16 bf16x8 __attribute__((ext_vector_type(8)));
typedef float f32x4 __attribute__((ext_vector_type(4)));

#define D_DIM 256
#define INV_T 2.0f

__device__ __forceinline__ unsigned short f2bf(float f) {
  union { float f; unsigned u; } x; x.f = f;
  unsigned r = x.u + 0x7FFFu + ((x.u >> 16) & 1u);  // round-to-nearest-even
  return (unsigned short)(r >> 16);
}

// ---------------- Kernel 1: L2-normalize [emb_i; emb_j] -> bf16 R[N][256] ----
__global__ __launch_bounds__(256) void k_normalize(const float* __restrict__ ei,
                                                   const float* __restrict__ ej,
                                                   unsigned short* __restrict__ R,
                                                   unsigned* __restrict__ ticket,
                                                   int B) {
  if (blockIdx.x == 0 && threadIdx.x == 0) *ticket = 0u;  // per-call reset
  const int w = threadIdx.x >> 6, lane = threadIdx.x & 63;
  const int row = blockIdx.x * 4 + w;
  const float* src = (row < B) ? (ei + (size_t)row * D_DIM)
                               : (ej + (size_t)(row - B) * D_DIM);
  float4 v = reinterpret_cast<const float4*>(src)[lane];  // 64 lanes * 4 = 256
  float ss = v.x * v.x + v.y * v.y + v.z * v.z + v.w * v.w;
#pragma unroll
  for (int d = 32; d; d >>= 1) ss += __shfl_xor(ss, d, 64);
  float s = 1.0f / fmaxf(sqrtf(ss), 1e-12f);
  ushort4 o;
  o.x = f2bf(v.x * s); o.y = f2bf(v.y * s);
  o.z = f2bf(v.z * s); o.w = f2bf(v.w * s);
  reinterpret_cast<ushort4*>(R + (size_t)row * D_DIM)[lane] = o;
}

// ---------------- Kernel 2: symmetric fused sim GEMM + exp partials ---------
// Only upper-triangular 128x128 tiles (bi <= bj). Each off-diagonal tile
// contributes exp-sums to BOTH its row block (reduce along cols) and its
// column block (reduce along rows, by symmetry of sim). Slots:
//   rowPartial[o*2 + u][row], o = other block, u = wc (row-dir) / wr (col-dir)
// Diagonal tiles: row-dir only. Every (slot,row) written exactly once.
// Single-buffer LDS (32KB) -> 4 blocks/CU; inter-block TLP hides staging.
__global__ __launch_bounds__(256, 4) void k_simgemm(const unsigned short* __restrict__ R,
                                                    float* __restrict__ rowPartial,
                                                    float* __restrict__ simTgt,
                                                    int N) {
  __shared__ char lds[32 * 1024];  // A tile 16KB + B tile 16KB
  const int tid = threadIdx.x;
  const int w = tid >> 6, lane = tid & 63;
  const int wr = w >> 1, wc = w & 1;
  const int half = N >> 1;

  // decode linear block id -> upper-triangular (bi, bj), bi <= bj
  const int T = N / 128;  // 64
  const int t = blockIdx.x;
  int bi = (int)(((float)(2 * T + 1) -
                  sqrtf((float)((2 * T + 1) * (2 * T + 1) - 8 * t))) * 0.5f);
  while (bi > 0 && t < bi * (2 * T - bi + 1) / 2) --bi;
  while (t >= (bi + 1) * (2 * T - bi) / 2) ++bi;
  const int bj = bi + (t - bi * (2 * T - bi + 1) / 2);
  const int brow = bi * 128, bcol = bj * 128;
  const bool offdiag = (bi != bj);

  f32x4 zero4 = {0.f, 0.f, 0.f, 0.f};
  f32x4 acc[4][4];
#pragma unroll
  for (int m = 0; m < 4; ++m)
#pragma unroll
    for (int n = 0; n < 4; ++n) acc[m][n] = zero4;

  // stage one BK=64 K-slice of the A (rows) and B (cols) panels into LDS.
  // Linear LDS dest (global_load_lds requirement) + inverse-XOR-swizzled
  // global source; reads apply the same swizzle (rule #21 both-sides).
  auto stage = [&](int kt) {
    char* ldsA = lds;
    char* ldsB = lds + 16 * 1024;
#pragma unroll
    for (int i = 0; i < 4; ++i) {
      const int grp = i * 4 + w;          // 16 chunk-groups of 64
      const int c = grp * 64 + lane;      // chunk id 0..1023
      const int r = c >> 3, j = c & 7;
      const int k8 = j ^ (r & 7);         // inverse swizzle on source
      const unsigned short* gA = R + (size_t)(brow + r) * D_DIM + kt * 64 + k8 * 8;
      const unsigned short* gB = R + (size_t)(bcol + r) * D_DIM + kt * 64 + k8 * 8;
      __builtin_amdgcn_global_load_lds(
          (const __attribute__((address_space(1))) void*)gA,
          (__attribute__((address_space(3))) void*)(ldsA + (size_t)grp * 1024), 16, 0, 0);
      __builtin_amdgcn_global_load_lds(
          (const __attribute__((address_space(1))) void*)gB,
          (__attribute__((address_space(3))) void*)(ldsB + (size_t)grp * 1024), 16, 0, 0);
    }
  };

  auto compute = [&]() {
    const char* ldsA = lds;
    const char* ldsB = lds + 16 * 1024;
#pragma unroll
    for (int kk = 0; kk < 2; ++kk) {
      const int k8 = kk * 4 + (lane >> 4);
      bf16x8 a[4], b[4];
#pragma unroll
      for (int m = 0; m < 4; ++m) {
        const int row = wr * 64 + m * 16 + (lane & 15);
        a[m] = *reinterpret_cast<const bf16x8*>(ldsA + (row * 8 + (k8 ^ (row & 7))) * 16);
      }
#pragma unroll
      for (int n = 0; n < 4; ++n) {
        const int col = wc * 64 + n * 16 + (lane & 15);
        b[n] = *reinterpret_cast<const bf16x8*>(ldsB + (col * 8 + (k8 ^ (col & 7))) * 16);
      }
#pragma unroll
      for (int m = 0; m < 4; ++m)
#pragma unroll
        for (int n = 0; n < 4; ++n)
          acc[m][n] = __builtin_amdgcn_mfma_f32_16x16x32_bf16(a[m], b[n], acc[m][n], 0, 0, 0);
    }
  };

#pragma unroll
  for (int kt = 0; kt < 4; ++kt) {  // K = 256 = 4 * 64
    stage(kt);
    __syncthreads();   // drains vmcnt -> LDS tile ready
    compute();
    __syncthreads();   // all reads done before next overwrite
  }

  // epilogue: scale, mask diag, capture targets (both directions), exp,
  // row-direction sums (over tile cols) + column-direction sums (over rows)
  float cs[4] = {0.f, 0.f, 0.f, 0.f};
#pragma unroll
  for (int m = 0; m < 4; ++m) {
#pragma unroll
    for (int j = 0; j < 4; ++j) {
      const int gr = brow + wr * 64 + m * 16 + (lane >> 4) * 4 + j;
      const int tgt = (gr < half) ? gr + half : gr - half;
      float rs = 0.f;
#pragma unroll
      for (int n = 0; n < 4; ++n) {
        const int gc = bcol + wc * 64 + n * 16 + (lane & 15);
        const float sv = acc[m][n][j] * INV_T;
        const float ev = (gr == gc) ? 0.f : __expf(sv);
        if (gc == tgt) {                 // involution: also gr == tgt(gc)
          simTgt[gr] = sv;
          if (offdiag) simTgt[gc] = sv;  // sim symmetric: sim[gc][gr] == sv
        }
        rs += ev;
        cs[n] += ev;
      }
#pragma unroll
      for (int d = 1; d < 16; d <<= 1) rs += __shfl_xor(rs, d, 64);
      if ((lane & 15) == 0)
        rowPartial[(size_t)(bj * 2 + wc) * N + gr] = rs;
    }
  }
  if (offdiag) {  // column block receives row-sums of the transposed tile
#pragma unroll
    for (int n = 0; n < 4; ++n) {
      float c = cs[n];
      c += __shfl_xor(c, 16, 64);
      c += __shfl_xor(c, 32, 64);
      if ((lane >> 4) == 0)
        rowPartial[(size_t)(bi * 2 + wr) * N + (bcol + wc * 64 + n * 16 + lane)] = c;
    }
  }
}

// ---------------- Kernel 3: row logsumexp-target + deterministic final mean --
__global__ __launch_bounds__(256) void k_rowreduce(const float* __restrict__ rowPartial,
                                                   const float* __restrict__ simTgt,
                                                   float* __restrict__ blockOut,
                                                   unsigned* __restrict__ ticket,
                                                   float* __restrict__ out, int N) {
  const int row = blockIdx.x * 256 + threadIdx.x;
  float denom = 0.f;
#pragma unroll 8
  for (int c = 0; c < 128; ++c) denom += rowPartial[(size_t)c * N + row];
  float lossr = __logf(denom) - simTgt[row];
#pragma unroll
  for (int d = 32; d; d >>= 1) lossr += __shfl_xor(lossr, d, 64);
  __shared__ float red[4];
  __shared__ int isLast;
  if ((threadIdx.x & 63) == 0) red[threadIdx.x >> 6] = lossr;
  __syncthreads();
  if (threadIdx.x == 0) {
    // device-scope RMW write: coherent across XCDs, deterministic value
    atomicExch(&blockOut[blockIdx.x], red[0] + red[1] + red[2] + red[3]);
    isLast = (atomicAdd(ticket, 1u) == gridDim.x - 1);
  }
  __syncthreads();
  if (isLast && threadIdx.x < 64) {
    // coherent read of every block sum via atomic RMW (+0.0f), fixed order
    float v = (threadIdx.x < gridDim.x) ? atomicAdd(&blockOut[threadIdx.x], 0.0f) : 0.f;
#pragma unroll
    for (int d = 32; d; d >>= 1) v += __shfl_xor(v, d, 64);
    if (threadIdx.x == 0) out[0] = v / (float)N;
  }
}

extern "C" void kernel_launch(void* const* d_in, const int* in_sizes, int n_in,
                              void* d_out, int out_size, void* d_ws, size_t ws_size,
                              hipStream_t stream) {
  const float* ei = (const float*)d_in[0];
  const float* ej = (const float*)d_in[1];
  const int B = in_sizes[0] / D_DIM;  // 4096
  const int N = 2 * B;                // 8192

  char* ws = (char*)d_ws;
  unsigned short* R = (unsigned short*)ws;                                   // N*256*2 = 4MB
  float* rowPartial = (float*)(ws + (size_t)N * D_DIM * 2);                  // 128*N*4 = 4MB
  float* simTgt     = (float*)(ws + (size_t)N * D_DIM * 2 + (size_t)128 * N * 4);  // N*4
  float* blockOut   = (float*)((char*)simTgt + (size_t)N * 4);               // (N/256)*4
  unsigned* ticket  = (unsigned*)((char*)blockOut + (size_t)(N / 256) * 4);  // 4B

  k_normalize<<<N / 4, 256, 0, stream>>>(ei, ej, R, ticket, B);
  const int T = N / 128;
  k_simgemm<<<T * (T + 1) / 2, 256, 0, stream>>>(R, rowPartial, simTgt, N);
  k_rowreduce<<<N / 256, 256, 0, stream>>>(rowPartial, simTgt, blockOut, ticket,
                                           (float*)d_out, N);
}

// Round 5
// 49.086 us; speedup vs baseline: 1.7428x; 1.0875x over previous
//
#include <hip/hip_runtime.h>

typedef __bf16 bf16x8 __attribute__((ext_vector_type(8)));
typedef float f32x4 __attribute__((ext_vector_type(4)));

#define D_DIM 256
// base-2 scale: sv2 = acc * INV_T * log2(e); exp(sv)=2^(sv2)
#define C2 2.88539008f
#define LN2 0.69314718f

__device__ __forceinline__ unsigned short f2bf(float f) {
  union { float f; unsigned u; } x; x.f = f;
  unsigned r = x.u + 0x7FFFu + ((x.u >> 16) & 1u);  // round-to-nearest-even
  return (unsigned short)(r >> 16);
}

// ---------------- Kernel 1: L2-normalize [emb_i; emb_j] -> bf16 R[N][256] ----
__global__ __launch_bounds__(256) void k_normalize(const float* __restrict__ ei,
                                                   const float* __restrict__ ej,
                                                   unsigned short* __restrict__ R,
                                                   unsigned* __restrict__ ticket,
                                                   int B) {
  if (blockIdx.x == 0 && threadIdx.x == 0) *ticket = 0u;  // per-call reset
  const int w = threadIdx.x >> 6, lane = threadIdx.x & 63;
  const int row = blockIdx.x * 4 + w;
  const float* src = (row < B) ? (ei + (size_t)row * D_DIM)
                               : (ej + (size_t)(row - B) * D_DIM);
  float4 v = reinterpret_cast<const float4*>(src)[lane];  // 64 lanes * 4 = 256
  float ss = v.x * v.x + v.y * v.y + v.z * v.z + v.w * v.w;
#pragma unroll
  for (int d = 32; d; d >>= 1) ss += __shfl_xor(ss, d, 64);
  float s = 1.0f / fmaxf(sqrtf(ss), 1e-12f);
  ushort4 o;
  o.x = f2bf(v.x * s); o.y = f2bf(v.y * s);
  o.z = f2bf(v.z * s); o.w = f2bf(v.w * s);
  reinterpret_cast<ushort4*>(R + (size_t)row * D_DIM)[lane] = o;
}

// ---------------- Kernel 2: symmetric fused sim GEMM + exp partials ---------
// Upper-triangular 128x128 tiles (bi <= bj); off-diag tiles feed both row and
// column blocks (sim symmetric). BK=32 double-buffered LDS (32KB total, 4
// blocks/CU) with counted vmcnt: next-tile loads stay in flight across
// barriers (T3/T4 minimum 2-phase).
__global__ __launch_bounds__(256, 4) void k_simgemm(const unsigned short* __restrict__ R,
                                                    float* __restrict__ rowPartial,
                                                    float* __restrict__ simTgt,
                                                    int N) {
  __shared__ char lds[2][16 * 1024];  // per buf: A panel 8KB + B panel 8KB
  const int tid = threadIdx.x;
  const int w = tid >> 6, lane = tid & 63;
  const int wr = w >> 1, wc = w & 1;
  const int half = N >> 1;

  // decode linear block id -> upper-triangular (bi, bj), bi <= bj
  const int T = N / 128;  // 64
  const int t = blockIdx.x;
  int bi = (int)(((float)(2 * T + 1) -
                  sqrtf((float)((2 * T + 1) * (2 * T + 1) - 8 * t))) * 0.5f);
  while (bi > 0 && t < bi * (2 * T - bi + 1) / 2) --bi;
  while (t >= (bi + 1) * (2 * T - bi) / 2) ++bi;
  const int bj = bi + (t - bi * (2 * T - bi + 1) / 2);
  const int brow = bi * 128, bcol = bj * 128;
  const bool offdiag = (bi != bj);

  f32x4 zero4 = {0.f, 0.f, 0.f, 0.f};
  f32x4 acc[4][4];
#pragma unroll
  for (int m = 0; m < 4; ++m)
#pragma unroll
    for (int n = 0; n < 4; ++n) acc[m][n] = zero4;

  // Stage one BK=32 K-slice (A panel rows, B panel cols) into lds[buf].
  // Row = 64B = 4 chunks of 16B. Swizzle: position js holds global chunk
  // j = js ^ ((r>>1)&3)  (involution; reader applies same XOR). Per 16-lane
  // group each bank-quad is hit exactly 2x -> conflict-free (m136).
  auto stage = [&](int buf, int kt) {
    char* dst = lds[buf];
#pragma unroll
    for (int i = 0; i < 4; ++i) {
      const int grp = i * 4 + w;              // 16 grps x 64 chunks of 16B
      const int cp = (grp & 7) * 64 + lane;   // chunk within panel, 0..511
      const int r = cp >> 2, js = cp & 3;
      const int j = js ^ ((r >> 1) & 3);      // inverse swizzle on source
      const int base = (grp < 8) ? brow : bcol;
      const unsigned short* g = R + (size_t)(base + r) * D_DIM + kt * 32 + j * 8;
      __builtin_amdgcn_global_load_lds(
          (const __attribute__((address_space(1))) void*)g,
          (__attribute__((address_space(3))) void*)(dst + (size_t)grp * 1024), 16, 0, 0);
    }
  };

  auto compute = [&](int buf) {
    const char* ldsA = lds[buf];
    const char* ldsB = lds[buf] + 8 * 1024;
    const int k8 = lane >> 4;  // k-chunk 0..3 (8 bf16 each)
    bf16x8 a[4], b[4];
#pragma unroll
    for (int m = 0; m < 4; ++m) {
      const int row = wr * 64 + m * 16 + (lane & 15);
      a[m] = *reinterpret_cast<const bf16x8*>(ldsA + (row * 4 + (k8 ^ ((row >> 1) & 3))) * 16);
    }
#pragma unroll
    for (int n = 0; n < 4; ++n) {
      const int col = wc * 64 + n * 16 + (lane & 15);
      b[n] = *reinterpret_cast<const bf16x8*>(ldsB + (col * 4 + (k8 ^ ((col >> 1) & 3))) * 16);
    }
#pragma unroll
    for (int m = 0; m < 4; ++m)
#pragma unroll
      for (int n = 0; n < 4; ++n)
        acc[m][n] = __builtin_amdgcn_mfma_f32_16x16x32_bf16(a[m], b[n], acc[m][n], 0, 0, 0);
  };

  stage(0, 0);  // prologue: 4 loads/wave in flight
#pragma unroll
  for (int kt = 0; kt < 8; ++kt) {  // K = 256 = 8 * 32
    const int cur = kt & 1;
    if (kt < 7) {
      stage(cur ^ 1, kt + 1);                       // +4 loads/wave in flight
      asm volatile("s_waitcnt vmcnt(4)" ::: "memory");  // cur buf landed
    } else {
      asm volatile("s_waitcnt vmcnt(0)" ::: "memory");
    }
    __builtin_amdgcn_s_barrier();   // all waves' cur-buf writes visible
    compute(cur);
    __builtin_amdgcn_s_barrier();   // all reads of cur done before overwrite
  }

  // epilogue (base-2): scale, mask diag, capture targets, exp2, row-direction
  // sums (over tile cols) + column-direction sums (over rows, symmetry)
  float cs[4] = {0.f, 0.f, 0.f, 0.f};
#pragma unroll
  for (int m = 0; m < 4; ++m) {
#pragma unroll
    for (int j = 0; j < 4; ++j) {
      const int gr = brow + wr * 64 + m * 16 + (lane >> 4) * 4 + j;
      const int tgt = (gr < half) ? gr + half : gr - half;
      float rs = 0.f;
#pragma unroll
      for (int n = 0; n < 4; ++n) {
        const int gc = bcol + wc * 64 + n * 16 + (lane & 15);
        const float sv2 = acc[m][n][j] * C2;
        const float ev = (gr == gc) ? 0.f : __builtin_amdgcn_exp2f(sv2);
        if (gc == tgt) {                  // involution: also gr == tgt(gc)
          simTgt[gr] = sv2;
          if (offdiag) simTgt[gc] = sv2;  // sim symmetric
        }
        rs += ev;
        cs[n] += ev;
      }
#pragma unroll
      for (int d = 1; d < 16; d <<= 1) rs += __shfl_xor(rs, d, 64);
      if ((lane & 15) == 0)
        rowPartial[(size_t)(bj * 2 + wc) * N + gr] = rs;
    }
  }
  if (offdiag) {  // column block receives row-sums of the transposed tile
#pragma unroll
    for (int n = 0; n < 4; ++n) {
      float c = cs[n];
      c += __shfl_xor(c, 16, 64);
      c += __shfl_xor(c, 32, 64);
      if ((lane >> 4) == 0)
        rowPartial[(size_t)(bi * 2 + wr) * N + (bcol + wc * 64 + n * 16 + lane)] = c;
    }
  }
}

// ---------------- Kernel 3: row logsumexp-target + deterministic final mean --
__global__ __launch_bounds__(256) void k_rowreduce(const float* __restrict__ rowPartial,
                                                   const float* __restrict__ simTgt,
                                                   float* __restrict__ blockOut,
                                                   unsigned* __restrict__ ticket,
                                                   float* __restrict__ out, int N) {
  const int row = blockIdx.x * 256 + threadIdx.x;
  float denom = 0.f;
#pragma unroll 8
  for (int c = 0; c < 128; ++c) denom += rowPartial[(size_t)c * N + row];
  // v_log_f32 = log2; loss = (log2(denom) - sv2) * ln2
  float lossr = (__builtin_amdgcn_logf(denom) - simTgt[row]) * LN2;
#pragma unroll
  for (int d = 32; d; d >>= 1) lossr += __shfl_xor(lossr, d, 64);
  __shared__ float red[4];
  __shared__ int isLast;
  if ((threadIdx.x & 63) == 0) red[threadIdx.x >> 6] = lossr;
  __syncthreads();
  if (threadIdx.x == 0) {
    // device-scope RMW write: coherent across XCDs, deterministic value
    atomicExch(&blockOut[blockIdx.x], red[0] + red[1] + red[2] + red[3]);
    isLast = (atomicAdd(ticket, 1u) == gridDim.x - 1);
  }
  __syncthreads();
  if (isLast && threadIdx.x < 64) {
    // coherent read of every block sum via atomic RMW (+0.0f), fixed order
    float v = (threadIdx.x < gridDim.x) ? atomicAdd(&blockOut[threadIdx.x], 0.0f) : 0.f;
#pragma unroll
    for (int d = 32; d; d >>= 1) v += __shfl_xor(v, d, 64);
    if (threadIdx.x == 0) out[0] = v / (float)N;
  }
}

extern "C" void kernel_launch(void* const* d_in, const int* in_sizes, int n_in,
                              void* d_out, int out_size, void* d_ws, size_t ws_size,
                              hipStream_t stream) {
  const float* ei = (const float*)d_in[0];
  const float* ej = (const float*)d_in[1];
  const int B = in_sizes[0] / D_DIM;  // 4096
  const int N = 2 * B;                // 8192

  char* ws = (char*)d_ws;
  unsigned short* R = (unsigned short*)ws;                                   // N*256*2 = 4MB
  float* rowPartial = (float*)(ws + (size_t)N * D_DIM * 2);                  // 128*N*4 = 4MB
  float* simTgt     = (float*)(ws + (size_t)N * D_DIM * 2 + (size_t)128 * N * 4);  // N*4
  float* blockOut   = (float*)((char*)simTgt + (size_t)N * 4);               // (N/256)*4
  unsigned* ticket  = (unsigned*)((char*)blockOut + (size_t)(N / 256) * 4);  // 4B

  k_normalize<<<N / 4, 256, 0, stream>>>(ei, ej, R, ticket, B);
  const int T = N / 128;
  k_simgemm<<<T * (T + 1) / 2, 256, 0, stream>>>(R, rowPartial, simTgt, N);
  k_rowreduce<<<N / 256, 256, 0, stream>>>(rowPartial, simTgt, blockOut, ticket,
                                           (float*)d_out, N);
}